// Round 1
// baseline (261.892 us; speedup 1.0000x reference)
//
#include <hip/hip_runtime.h>

#define S_LEN  2048
#define DMODEL 1024
#define NHEAD  16
#define DHEAD  64
#define SCALE_F 0.125f

typedef unsigned short ushort_t;
typedef __attribute__((ext_vector_type(8))) short bf16x8;
typedef __attribute__((ext_vector_type(4))) float f32x4;

__device__ __forceinline__ ushort_t f2bf(float f) {
    unsigned u = __builtin_bit_cast(unsigned, f);
    unsigned r = (u + 0x7FFFu + ((u >> 16) & 1u)) >> 16;
    return (ushort_t)r;
}

__global__ void cast_f32_bf16(const float* __restrict__ in, ushort_t* __restrict__ out, int n4) {
    int i = blockIdx.x * blockDim.x + threadIdx.x;
    int stride = gridDim.x * blockDim.x;
    for (int idx = i; idx < n4; idx += stride) {
        float4 f = ((const float4*)in)[idx];
        ushort4 o;
        o.x = f2bf(f.x); o.y = f2bf(f.y); o.z = f2bf(f.z); o.w = f2bf(f.w);
        ((ushort4*)out)[idx] = o;
    }
}

// C = A @ B^T + bias.  A: [M][K] bf16 row-major, Bw: [N][K] bf16 row-major.
// MODE 0: out = bf16, head-split   [B][H][S][DH]   (for Q, K)
// MODE 1: out = bf16, head-split-T [B][H][DH][S]   (for V -> Vt)
// MODE 2: out = f32 flat [M][N]                    (final output)
template<int MODE>
__launch_bounds__(256)
__global__ void gemm_bt(const ushort_t* __restrict__ A, const ushort_t* __restrict__ Bw,
                        const float* __restrict__ bias, void* __restrict__ out,
                        int M, int N, int K) {
    __shared__ ushort_t As[128][40];   // +8 pad: conflict-free b128 frag reads
    __shared__ ushort_t Bs[128][40];
    const int tid  = threadIdx.x;
    const int lane = tid & 63;
    const int w    = tid >> 6;
    const int wr   = w >> 1, wc = w & 1;
    const int m0   = blockIdx.x * 128;
    const int n0   = blockIdx.y * 128;
    const int l15  = lane & 15;
    const int lg   = lane >> 4;

    f32x4 acc[4][4] = {};

    const int sr = tid >> 2;          // 0..63
    const int sc = (tid & 3) * 8;     // 0,8,16,24

    for (int k0 = 0; k0 < K; k0 += 32) {
        *(uint4*)&As[sr][sc]      = *(const uint4*)(A  + (size_t)(m0 + sr)      * K + k0 + sc);
        *(uint4*)&As[sr + 64][sc] = *(const uint4*)(A  + (size_t)(m0 + sr + 64) * K + k0 + sc);
        *(uint4*)&Bs[sr][sc]      = *(const uint4*)(Bw + (size_t)(n0 + sr)      * K + k0 + sc);
        *(uint4*)&Bs[sr + 64][sc] = *(const uint4*)(Bw + (size_t)(n0 + sr + 64) * K + k0 + sc);
        __syncthreads();
        bf16x8 af[4], bf[4];
#pragma unroll
        for (int i = 0; i < 4; i++) {
            af[i] = *(const bf16x8*)&As[wr*64 + i*16 + l15][lg*8];
            bf[i] = *(const bf16x8*)&Bs[wc*64 + i*16 + l15][lg*8];
        }
#pragma unroll
        for (int mf = 0; mf < 4; mf++)
#pragma unroll
            for (int nf = 0; nf < 4; nf++)
                acc[mf][nf] = __builtin_amdgcn_mfma_f32_16x16x32_bf16(af[mf], bf[nf], acc[mf][nf], 0, 0, 0);
        __syncthreads();
    }

#pragma unroll
    for (int mf = 0; mf < 4; mf++) {
#pragma unroll
        for (int nf = 0; nf < 4; nf++) {
            const int col = n0 + wc*64 + nf*16 + l15;
            const float bv = bias[col];
#pragma unroll
            for (int r = 0; r < 4; r++) {
                const int row = m0 + wr*64 + mf*16 + lg*4 + r;
                const float v = acc[mf][nf][r] + bv;
                if constexpr (MODE == 2) {
                    ((float*)out)[(size_t)row * N + col] = v;
                } else {
                    const int b = row >> 11, s = row & 2047;   // S=2048
                    const int h = col >> 6,  dh = col & 63;    // DH=64
                    if constexpr (MODE == 0)
                        ((ushort_t*)out)[((size_t)(b*NHEAD + h) * S_LEN + s) * DHEAD + dh] = f2bf(v);
                    else
                        ((ushort_t*)out)[((size_t)(b*NHEAD + h) * DHEAD + dh) * S_LEN + s] = f2bf(v);
                }
            }
        }
    }
}

// Flash attention, causal. Q,K: [B][H][S][DH] bf16. Vt: [B][H][DH][S] bf16.
// Aout: [B][S][D] bf16 (heads merged).
__launch_bounds__(256)
__global__ void attn_fwd(const ushort_t* __restrict__ Q, const ushort_t* __restrict__ Kh,
                         const ushort_t* __restrict__ Vt, ushort_t* __restrict__ Aout) {
    __shared__ ushort_t Ks[64][72];
    __shared__ ushort_t Vs[64][72];          // Vt tile: [dh][kv]
    __shared__ ushort_t Ps[4][32][72];       // per-wave P round-trip
    const int tid  = threadIdx.x;
    const int lane = tid & 63;
    const int w    = tid >> 6;
    const int l15  = lane & 15, lg = lane >> 4;
    const int bh   = blockIdx.y;             // b*H + h
    const int q0   = blockIdx.x * 128;
    const int qw   = q0 + w * 32;
    const size_t qkbase = (size_t)bh * S_LEN * DHEAD;
    const size_t vtbase = (size_t)bh * DHEAD * S_LEN;

    // Q fragments live in registers for the whole block
    bf16x8 aq[2][2];
#pragma unroll
    for (int mf = 0; mf < 2; mf++)
#pragma unroll
        for (int kc = 0; kc < 2; kc++)
            aq[mf][kc] = *(const bf16x8*)(Q + qkbase + (size_t)(qw + mf*16 + l15) * DHEAD + kc*32 + lg*8);

    float mrow[2][4], lrow[2][4];
    f32x4 o[2][4] = {};
#pragma unroll
    for (int mf = 0; mf < 2; mf++)
#pragma unroll
        for (int r = 0; r < 4; r++) { mrow[mf][r] = -3.0e38f; lrow[mf][r] = 0.0f; }

    const int nt = q0 / 64 + 2;              // causal: kv tiles up to block diagonal
    const int sr = tid >> 3;                 // 0..31
    const int sc = (tid & 7) * 8;            // 0..56

    for (int t = 0; t < nt; t++) {
        const int kv0 = t * 64;
#pragma unroll
        for (int i = 0; i < 2; i++) {
            const int r = sr + i * 32;
            *(uint4*)&Ks[r][sc] = *(const uint4*)(Kh + qkbase + (size_t)(kv0 + r) * DHEAD + sc);
            *(uint4*)&Vs[r][sc] = *(const uint4*)(Vt + vtbase + (size_t)r * S_LEN + kv0 + sc);
        }
        __syncthreads();

        // S = Q K^T (per wave: 32 q-rows x 64 kv-cols)
        f32x4 sacc[2][4] = {};
#pragma unroll
        for (int nf = 0; nf < 4; nf++)
#pragma unroll
            for (int kc = 0; kc < 2; kc++) {
                bf16x8 bk = *(const bf16x8*)&Ks[nf*16 + l15][kc*32 + lg*8];
#pragma unroll
                for (int mf = 0; mf < 2; mf++)
                    sacc[mf][nf] = __builtin_amdgcn_mfma_f32_16x16x32_bf16(aq[mf][kc], bk, sacc[mf][nf], 0, 0, 0);
            }

        // scale + causal mask + online softmax
#pragma unroll
        for (int mf = 0; mf < 2; mf++) {
            float mx[4] = {-3.0e38f, -3.0e38f, -3.0e38f, -3.0e38f};
#pragma unroll
            for (int nf = 0; nf < 4; nf++) {
                const int colk = kv0 + nf*16 + l15;
#pragma unroll
                for (int r = 0; r < 4; r++) {
                    const int rowq = qw + mf*16 + lg*4 + r;
                    float v = sacc[mf][nf][r] * SCALE_F;
                    if (colk > rowq) v = -3.0e38f;
                    sacc[mf][nf][r] = v;
                    mx[r] = fmaxf(mx[r], v);
                }
            }
#pragma unroll
            for (int r = 0; r < 4; r++)
#pragma unroll
                for (int m = 1; m < 16; m <<= 1) mx[r] = fmaxf(mx[r], __shfl_xor(mx[r], m));

            float corr[4], rs[4];
#pragma unroll
            for (int r = 0; r < 4; r++) {
                const float mn = fmaxf(mrow[mf][r], mx[r]);
                corr[r] = __expf(mrow[mf][r] - mn);
                mrow[mf][r] = mn;
                rs[r] = 0.0f;
            }
#pragma unroll
            for (int nf = 0; nf < 4; nf++)
#pragma unroll
                for (int r = 0; r < 4; r++) {
                    const float p = __expf(sacc[mf][nf][r] - mrow[mf][r]);
                    rs[r] += p;
                    Ps[w][mf*16 + lg*4 + r][nf*16 + l15] = f2bf(p);
                }
#pragma unroll
            for (int r = 0; r < 4; r++) {
#pragma unroll
                for (int m = 1; m < 16; m <<= 1) rs[r] += __shfl_xor(rs[r], m);
                lrow[mf][r] = lrow[mf][r] * corr[r] + rs[r];
            }
#pragma unroll
            for (int nf = 0; nf < 4; nf++)
#pragma unroll
                for (int r = 0; r < 4; r++) o[mf][nf][r] *= corr[r];
        }

        // O += P @ V   (A-frag from Ps, B-frag from Vt tile: contiguous reads)
#pragma unroll
        for (int mf = 0; mf < 2; mf++)
#pragma unroll
            for (int kc = 0; kc < 2; kc++) {
                bf16x8 pa = *(const bf16x8*)&Ps[w][mf*16 + l15][kc*32 + lg*8];
#pragma unroll
                for (int nf = 0; nf < 4; nf++) {
                    bf16x8 bv = *(const bf16x8*)&Vs[nf*16 + l15][kc*32 + lg*8];
                    o[mf][nf] = __builtin_amdgcn_mfma_f32_16x16x32_bf16(pa, bv, o[mf][nf], 0, 0, 0);
                }
            }
        __syncthreads();
    }

    // epilogue: O /= l, merge heads
    const int b = bh >> 4, h = bh & 15;
#pragma unroll
    for (int mf = 0; mf < 2; mf++)
#pragma unroll
        for (int r = 0; r < 4; r++) {
            const float inv = 1.0f / lrow[mf][r];
            const int rowq = qw + mf*16 + lg*4 + r;
#pragma unroll
            for (int nf = 0; nf < 4; nf++) {
                const float v = o[mf][nf][r] * inv;
                Aout[((size_t)(b * S_LEN) + rowq) * DMODEL + h*DHEAD + nf*16 + l15] = f2bf(v);
            }
        }
}

extern "C" void kernel_launch(void* const* d_in, const int* in_sizes, int n_in,
                              void* d_out, int out_size, void* d_ws, size_t ws_size,
                              hipStream_t stream) {
    (void)in_sizes; (void)n_in; (void)out_size; (void)ws_size;
    const float* x  = (const float*)d_in[0];
    // d_in[1] = mask: causal triu, computed analytically instead
    const float* Wq = (const float*)d_in[2];
    const float* bq = (const float*)d_in[3];
    const float* Wk = (const float*)d_in[4];
    const float* bk = (const float*)d_in[5];
    const float* Wv = (const float*)d_in[6];
    const float* bv = (const float*)d_in[7];
    const float* Wo = (const float*)d_in[8];
    const float* bo = (const float*)d_in[9];

    char* ws = (char*)d_ws;
    ushort_t* xb  = (ushort_t*)(ws);                 // 4096x1024 bf16   (8 MB)
    ushort_t* Wqb = (ushort_t*)(ws + (8u  << 20));   // 1024x1024 bf16   (2 MB)
    ushort_t* Wkb = (ushort_t*)(ws + (10u << 20));
    ushort_t* Wvb = (ushort_t*)(ws + (12u << 20));
    ushort_t* Wob = (ushort_t*)(ws + (14u << 20));
    ushort_t* Qh  = (ushort_t*)(ws + (16u << 20));   // [B][H][S][DH]    (8 MB)
    ushort_t* Kh  = (ushort_t*)(ws + (24u << 20));   // [B][H][S][DH]    (8 MB)
    ushort_t* Vth = (ushort_t*)(ws + (32u << 20));   // [B][H][DH][S]    (8 MB)
    ushort_t* Ao  = (ushort_t*)(ws + (40u << 20));   // [B][S][D] bf16   (8 MB)

    cast_f32_bf16<<<2048, 256, 0, stream>>>(x,  xb,  (2*S_LEN*DMODEL) / 4);
    cast_f32_bf16<<<1024, 256, 0, stream>>>(Wq, Wqb, (DMODEL*DMODEL) / 4);
    cast_f32_bf16<<<1024, 256, 0, stream>>>(Wk, Wkb, (DMODEL*DMODEL) / 4);
    cast_f32_bf16<<<1024, 256, 0, stream>>>(Wv, Wvb, (DMODEL*DMODEL) / 4);
    cast_f32_bf16<<<1024, 256, 0, stream>>>(Wo, Wob, (DMODEL*DMODEL) / 4);

    dim3 g(32, 8);  // M/128, N/128
    gemm_bt<0><<<g, 256, 0, stream>>>(xb, Wqb, bq, Qh,  2*S_LEN, DMODEL, DMODEL);
    gemm_bt<0><<<g, 256, 0, stream>>>(xb, Wkb, bk, Kh,  2*S_LEN, DMODEL, DMODEL);
    gemm_bt<1><<<g, 256, 0, stream>>>(xb, Wvb, bv, Vth, 2*S_LEN, DMODEL, DMODEL);

    attn_fwd<<<dim3(S_LEN/128, 2*NHEAD), 256, 0, stream>>>(Qh, Kh, Vth, Ao);

    gemm_bt<2><<<g, 256, 0, stream>>>(Ao, Wob, bo, d_out, 2*S_LEN, DMODEL, DMODEL);
}

// Round 2
// 209.151 us; speedup vs baseline: 1.2522x; 1.2522x over previous
//
#include <hip/hip_runtime.h>

#define S_LEN  2048
#define DMODEL 1024
#define NHEAD  16
#define DHEAD  64
#define SCALE_F 0.125f

typedef unsigned short ushort_t;
typedef __attribute__((ext_vector_type(8))) short bf16x8;
typedef __attribute__((ext_vector_type(4))) float f32x4;

typedef __attribute__((address_space(1))) void gv_t;
typedef __attribute__((address_space(3))) void lv_t;

__device__ __forceinline__ ushort_t f2bf(float f) {
    unsigned u = __builtin_bit_cast(unsigned, f);
    unsigned r = (u + 0x7FFFu + ((u >> 16) & 1u)) >> 16;
    return (ushort_t)r;
}

__device__ __forceinline__ void gload16(const ushort_t* g, ushort_t* l) {
    __builtin_amdgcn_global_load_lds((gv_t*)g, (lv_t*)l, 16, 0, 0);
}

// Cast x, Wq, Wk, Wv, Wo (f32) into one contiguous bf16 region:
// [xb (4096x1024) | Wqkv (3072x1024) | Wo (1024x1024)]
__global__ void cast_all(const float* __restrict__ x,
                         const float* __restrict__ Wq, const float* __restrict__ Wk,
                         const float* __restrict__ Wv, const float* __restrict__ Wo,
                         ushort_t* __restrict__ dst, int n4) {
    int i = blockIdx.x * blockDim.x + threadIdx.x;
    int stride = gridDim.x * blockDim.x;
    for (int idx = i; idx < n4; idx += stride) {
        const float* src; int off;
        if (idx < 1048576)      { src = x;  off = idx; }
        else if (idx < 1310720) { src = Wq; off = idx - 1048576; }
        else if (idx < 1572864) { src = Wk; off = idx - 1310720; }
        else if (idx < 1835008) { src = Wv; off = idx - 1572864; }
        else                    { src = Wo; off = idx - 1835008; }
        float4 f = ((const float4*)src)[off];
        ushort4 o;
        o.x = f2bf(f.x); o.y = f2bf(f.y); o.z = f2bf(f.z); o.w = f2bf(f.w);
        ((ushort4*)dst)[idx] = o;
    }
}

// C = A @ B^T + bias.  A: [M][K] bf16, Bw: [N][K] bf16 (row-major, K-contig).
// MODE 0 (BM=128): fused QKV epilogue, N=3072: mat=col>>10 selects Q/K/V dest.
//   Q,K -> [B][H][S][DH] bf16;  V -> [B][H][DH][S] bf16 (transposed).
// MODE 2 (BM=64): out0 = f32 flat [M][N].
template<int MODE, int BM>
__launch_bounds__(256)
__global__ void gemm_bt(const ushort_t* __restrict__ A, const ushort_t* __restrict__ Bw,
                        const float* __restrict__ b0, const float* __restrict__ b1,
                        const float* __restrict__ b2,
                        void* __restrict__ out0, void* __restrict__ out1, void* __restrict__ out2,
                        int M, int N, int K) {
    constexpr int MF = BM / 32;                 // A-frags per wave
    __shared__ ushort_t As[BM][32];             // linear: global_load_lds friendly
    __shared__ ushort_t Bs[128][32];
    const int tid  = threadIdx.x;
    const int lane = tid & 63;
    const int w    = tid >> 6;
    const int wr   = w >> 1, wc = w & 1;        // 2x2 wave grid
    const int m0   = blockIdx.x * BM;
    const int n0   = blockIdx.y * 128;
    const int l15  = lane & 15;
    const int lg   = lane >> 4;
    const int srow = lane >> 2;                 // staging: row within 16-row chunk
    const int scol = (lane & 3) * 8;            // staging: col

    f32x4 acc[MF][4] = {};

    for (int k0 = 0; k0 < K; k0 += 32) {
        // stage A: BM rows, 64B each; each gload16 covers 16 rows per wave
#pragma unroll
        for (int j = 0; j < BM / 64; j++) {
            const int rbase = w * (BM / 4) + j * 16;
            gload16(A + (size_t)(m0 + rbase + srow) * K + k0 + scol, &As[rbase][0]);
        }
#pragma unroll
        for (int j = 0; j < 2; j++) {
            const int rbase = w * 32 + j * 16;
            gload16(Bw + (size_t)(n0 + rbase + srow) * K + k0 + scol, &Bs[rbase][0]);
        }
        __syncthreads();
        bf16x8 af[MF], bfr[4];
#pragma unroll
        for (int i = 0; i < MF; i++) af[i]  = *(const bf16x8*)&As[wr*(BM/2) + i*16 + l15][lg*8];
#pragma unroll
        for (int i = 0; i < 4;  i++) bfr[i] = *(const bf16x8*)&Bs[wc*64 + i*16 + l15][lg*8];
#pragma unroll
        for (int mf = 0; mf < MF; mf++)
#pragma unroll
            for (int nf = 0; nf < 4; nf++)
                acc[mf][nf] = __builtin_amdgcn_mfma_f32_16x16x32_bf16(af[mf], bfr[nf], acc[mf][nf], 0, 0, 0);
        __syncthreads();
    }

#pragma unroll
    for (int mf = 0; mf < MF; mf++) {
#pragma unroll
        for (int nf = 0; nf < 4; nf++) {
            const int col = n0 + wc*64 + nf*16 + l15;
            if constexpr (MODE == 2) {
                const float bv = b0[col];
#pragma unroll
                for (int r = 0; r < 4; r++) {
                    const int row = m0 + wr*(BM/2) + mf*16 + lg*4 + r;
                    ((float*)out0)[(size_t)row * N + col] = acc[mf][nf][r] + bv;
                }
            } else {
                const int mat = col >> 10;                  // 0=Q 1=K 2=V
                const int c   = col & 1023;
                const int h   = c >> 6, dh = c & 63;
                const float* bp = (mat == 0) ? b0 : ((mat == 1) ? b1 : b2);
                const float bv = bp[c];
#pragma unroll
                for (int r = 0; r < 4; r++) {
                    const int row = m0 + wr*(BM/2) + mf*16 + lg*4 + r;
                    const int b = row >> 11, s = row & 2047;
                    const float v = acc[mf][nf][r] + bv;
                    if (mat == 0)
                        ((ushort_t*)out0)[((size_t)(b*NHEAD + h) * S_LEN + s) * DHEAD + dh] = f2bf(v);
                    else if (mat == 1)
                        ((ushort_t*)out1)[((size_t)(b*NHEAD + h) * S_LEN + s) * DHEAD + dh] = f2bf(v);
                    else
                        ((ushort_t*)out2)[((size_t)(b*NHEAD + h) * DHEAD + dh) * S_LEN + s] = f2bf(v);
                }
            }
        }
    }
}

// Flash attention, causal. Q,K: [B][H][S][DH] bf16. Vt: [B][H][DH][S] bf16.
// 64 q-rows per block (16 per wave); heavy q-tiles dispatched first (LPT).
__launch_bounds__(256)
__global__ void attn_fwd(const ushort_t* __restrict__ Q, const ushort_t* __restrict__ Kh,
                         const ushort_t* __restrict__ Vt, ushort_t* __restrict__ Aout) {
    __shared__ ushort_t Ks[64][72];
    __shared__ ushort_t Vs[64][72];          // Vt tile: [dh][kv]
    __shared__ ushort_t Ps[4][16][72];       // per-wave P round-trip
    const int tid  = threadIdx.x;
    const int lane = tid & 63;
    const int w    = tid >> 6;
    const int l15  = lane & 15, lg = lane >> 4;
    const int bh   = blockIdx.y;             // b*H + h
    const int qt   = (gridDim.x - 1) - blockIdx.x;   // reversed: long blocks first
    const int q0   = qt * 64;
    const int qw   = q0 + w * 16;
    const size_t qkbase = (size_t)bh * S_LEN * DHEAD;
    const size_t vtbase = (size_t)bh * DHEAD * S_LEN;

    bf16x8 aq[2];
#pragma unroll
    for (int kc = 0; kc < 2; kc++)
        aq[kc] = *(const bf16x8*)(Q + qkbase + (size_t)(qw + l15) * DHEAD + kc*32 + lg*8);

    float mrow[4], lrow[4];
    f32x4 o[4] = {};
#pragma unroll
    for (int r = 0; r < 4; r++) { mrow[r] = -3.0e38f; lrow[r] = 0.0f; }

    const int nt = qt + 1;
    const int sr = tid >> 3;                 // 0..31
    const int sc = (tid & 7) * 8;            // 0..56

    for (int t = 0; t < nt; t++) {
        const int kv0 = t * 64;
#pragma unroll
        for (int i = 0; i < 2; i++) {
            const int r = sr + i * 32;
            *(uint4*)&Ks[r][sc] = *(const uint4*)(Kh + qkbase + (size_t)(kv0 + r) * DHEAD + sc);
            *(uint4*)&Vs[r][sc] = *(const uint4*)(Vt + vtbase + (size_t)r * S_LEN + kv0 + sc);
        }
        __syncthreads();

        // S = Q K^T  (16 q-rows x 64 kv-cols per wave)
        f32x4 sacc[4] = {};
#pragma unroll
        for (int nf = 0; nf < 4; nf++)
#pragma unroll
            for (int kc = 0; kc < 2; kc++) {
                bf16x8 bk = *(const bf16x8*)&Ks[nf*16 + l15][kc*32 + lg*8];
                sacc[nf] = __builtin_amdgcn_mfma_f32_16x16x32_bf16(aq[kc], bk, sacc[nf], 0, 0, 0);
            }

        // scale + causal mask + online softmax
        float mx[4] = {-3.0e38f, -3.0e38f, -3.0e38f, -3.0e38f};
#pragma unroll
        for (int nf = 0; nf < 4; nf++) {
            const int colk = kv0 + nf*16 + l15;
#pragma unroll
            for (int r = 0; r < 4; r++) {
                const int rowq = qw + lg*4 + r;
                float v = sacc[nf][r] * SCALE_F;
                if (colk > rowq) v = -3.0e38f;
                sacc[nf][r] = v;
                mx[r] = fmaxf(mx[r], v);
            }
        }
#pragma unroll
        for (int r = 0; r < 4; r++)
#pragma unroll
            for (int m = 1; m < 16; m <<= 1) mx[r] = fmaxf(mx[r], __shfl_xor(mx[r], m));

        float corr[4], rs[4];
#pragma unroll
        for (int r = 0; r < 4; r++) {
            const float mn = fmaxf(mrow[r], mx[r]);
            corr[r] = __expf(mrow[r] - mn);
            mrow[r] = mn;
            rs[r] = 0.0f;
        }
#pragma unroll
        for (int nf = 0; nf < 4; nf++)
#pragma unroll
            for (int r = 0; r < 4; r++) {
                const float p = __expf(sacc[nf][r] - mrow[r]);
                rs[r] += p;
                Ps[w][lg*4 + r][nf*16 + l15] = f2bf(p);
            }
#pragma unroll
        for (int r = 0; r < 4; r++) {
#pragma unroll
            for (int m = 1; m < 16; m <<= 1) rs[r] += __shfl_xor(rs[r], m);
            lrow[r] = lrow[r] * corr[r] + rs[r];
        }
#pragma unroll
        for (int nf = 0; nf < 4; nf++)
#pragma unroll
            for (int r = 0; r < 4; r++) o[nf][r] *= corr[r];

        // O += P @ V
#pragma unroll
        for (int kc = 0; kc < 2; kc++) {
            bf16x8 pa = *(const bf16x8*)&Ps[w][l15][kc*32 + lg*8];
#pragma unroll
            for (int nf = 0; nf < 4; nf++) {
                bf16x8 bv = *(const bf16x8*)&Vs[nf*16 + l15][kc*32 + lg*8];
                o[nf] = __builtin_amdgcn_mfma_f32_16x16x32_bf16(pa, bv, o[nf], 0, 0, 0);
            }
        }
        __syncthreads();
    }

    // epilogue: O /= l, merge heads
    const int b = bh >> 4, h = bh & 15;
#pragma unroll
    for (int r = 0; r < 4; r++) {
        const float inv = 1.0f / lrow[r];
        const int rowq = qw + lg*4 + r;
#pragma unroll
        for (int nf = 0; nf < 4; nf++) {
            const float v = o[nf][r] * inv;
            Aout[((size_t)(b * S_LEN) + rowq) * DMODEL + h*DHEAD + nf*16 + l15] = f2bf(v);
        }
    }
}

extern "C" void kernel_launch(void* const* d_in, const int* in_sizes, int n_in,
                              void* d_out, int out_size, void* d_ws, size_t ws_size,
                              hipStream_t stream) {
    (void)in_sizes; (void)n_in; (void)out_size; (void)ws_size;
    const float* x  = (const float*)d_in[0];
    // d_in[1] = mask: causal triu, computed analytically
    const float* Wq = (const float*)d_in[2];
    const float* bq = (const float*)d_in[3];
    const float* Wk = (const float*)d_in[4];
    const float* bk = (const float*)d_in[5];
    const float* Wv = (const float*)d_in[6];
    const float* bv = (const float*)d_in[7];
    const float* Wo = (const float*)d_in[8];
    const float* bo = (const float*)d_in[9];

    char* ws = (char*)d_ws;
    ushort_t* xb    = (ushort_t*)(ws);                 // 4096x1024 bf16  (8 MB)
    ushort_t* Wqkvb = (ushort_t*)(ws + (8u  << 20));   // 3072x1024 bf16  (6 MB)
    ushort_t* Wob   = (ushort_t*)(ws + (14u << 20));   // 1024x1024 bf16  (2 MB)
    ushort_t* Qh    = (ushort_t*)(ws + (16u << 20));   // [B][H][S][DH]   (8 MB)
    ushort_t* Kh    = (ushort_t*)(ws + (24u << 20));   // [B][H][S][DH]   (8 MB)
    ushort_t* Vth   = (ushort_t*)(ws + (32u << 20));   // [B][H][DH][S]   (8 MB)
    ushort_t* Ao    = (ushort_t*)(ws + (40u << 20));   // [B][S][D] bf16  (8 MB)

    cast_all<<<2048, 256, 0, stream>>>(x, Wq, Wk, Wv, Wo, xb, 2097152);

    // fused QKV projection: N = 3072
    gemm_bt<0, 128><<<dim3(32, 24), 256, 0, stream>>>(xb, Wqkvb, bq, bk, bv,
                                                      Qh, Kh, Vth, 2*S_LEN, 3*DMODEL, DMODEL);

    attn_fwd<<<dim3(S_LEN/64, 2*NHEAD), 256, 0, stream>>>(Qh, Kh, Vth, Ao);

    // output projection -> f32
    gemm_bt<2, 64><<<dim3(64, 8), 256, 0, stream>>>(Ao, Wob, bo, nullptr, nullptr,
                                                    d_out, nullptr, nullptr, 2*S_LEN, DMODEL, DMODEL);
}